// Round 4
// baseline (704.710 us; speedup 1.0000x reference)
//
#include <hip/hip_runtime.h>

// Nearest-prototype argmin: N=500k, K=256, D=64, fp32.
// R4: back to the proven R2 numerics, but mus streamed through the VECTOR
// memory path (uniform-address float4 VMEM loads -> single 16B request,
// L1-broadcast, compiler-pipelined vmcnt) instead of the scalar pipe, which
// R2 showed is queue-limited (~1100 cyc effective per iteration). 3 points
// per thread triples FMA work per mu byte and cuts wave count 3x. No inline
// asm pipelining (R3's failure: allocator copies can read in-flight SMEM
// destinations -- unfixable at HIP level).

#define KPROTO 256
#define DIM 64
#define PTS 3
#define BLK 256

__global__ void musq_kernel(const float* __restrict__ mus,
                            float* __restrict__ musq) {
    int k = threadIdx.x;  // one block of 256
    const float4* m4 = (const float4*)(mus + k * DIM);
    float a0 = 0.f, a1 = 0.f, a2 = 0.f, a3 = 0.f;
#pragma unroll
    for (int q = 0; q < DIM / 4; ++q) {
        float4 v = m4[q];
        a0 = fmaf(v.x, v.x, a0);
        a1 = fmaf(v.y, v.y, a1);
        a2 = fmaf(v.z, v.z, a2);
        a3 = fmaf(v.w, v.w, a3);
    }
    musq[k] = (a0 + a1) + (a2 + a3);
}

__launch_bounds__(BLK, 2)
__global__ void argmin_kernel(const float* __restrict__ X,
                              const float* __restrict__ mus,
                              const float* __restrict__ musq,
                              int* __restrict__ out, int n) {
    const int tid = threadIdx.x;
    const int base = blockIdx.x * (BLK * PTS) + tid;

    // Opaque zero in a VGPR: defeats uniformity analysis so the mu loads
    // stay on the VMEM path (coalesced broadcast via L1) instead of being
    // scalarized to s_load (R2's queue-limited scalar path).
    int vzero;
    asm("v_mov_b32 %0, 0" : "=v"(vzero));

    // x for PTS points -> registers (all indices compile-time constant).
    float4 xv[PTS][16];
    float xsq[PTS];
#pragma unroll
    for (int p = 0; p < PTS; ++p) {
        const int i = base + p * BLK;
        const int r = (i < n) ? i : (n - 1);  // OOB lanes compute, don't store
        const float4* xp = (const float4*)(X + (size_t)r * DIM);
#pragma unroll
        for (int q = 0; q < 16; ++q) xv[p][q] = xp[q];
        float a0 = 0.f, a1 = 0.f, a2 = 0.f, a3 = 0.f;
#pragma unroll
        for (int q = 0; q < 16; ++q) {
            float4 v = xv[p][q];
            a0 = fmaf(v.x, v.x, a0);
            a1 = fmaf(v.y, v.y, a1);
            a2 = fmaf(v.z, v.z, a2);
            a3 = fmaf(v.w, v.w, a3);
        }
        xsq[p] = (a0 + a1) + (a2 + a3);
    }

    float best[PTS];
    int bidx[PTS];
#pragma unroll
    for (int p = 0; p < PTS; ++p) { best[p] = 3.4e38f; bidx[p] = 0; }

    for (int k = 0; k < KPROTO; ++k) {
        // divergent-looking (but runtime-uniform) address -> VMEM broadcast
        const float4* m4 = (const float4*)(mus + (size_t)(k * DIM + vzero));
        float acc[PTS][4];
#pragma unroll
        for (int p = 0; p < PTS; ++p) {
            acc[p][0] = 0.f; acc[p][1] = 0.f; acc[p][2] = 0.f; acc[p][3] = 0.f;
        }
#pragma unroll
        for (int q = 0; q < 16; ++q) {
            const float4 mv = m4[q];
#pragma unroll
            for (int p = 0; p < PTS; ++p) {
                // same striped accumulation order as R1/R2 (absmax=0 proven):
                // acc0 <- elements 0,4,8,... ; acc1 <- 1,5,9,... ; etc.
                acc[p][0] = fmaf(mv.x, xv[p][q].x, acc[p][0]);
                acc[p][1] = fmaf(mv.y, xv[p][q].y, acc[p][1]);
                acc[p][2] = fmaf(mv.z, xv[p][q].z, acc[p][2]);
                acc[p][3] = fmaf(mv.w, xv[p][q].w, acc[p][3]);
            }
        }
        const float msq = musq[k];
#pragma unroll
        for (int p = 0; p < PTS; ++p) {
            const float dot = (acc[p][0] + acc[p][1]) + (acc[p][2] + acc[p][3]);
            // mirror np rounding: (x_sq - 2*dot) then + mu_sq (2*dot exact)
            const float d2 = (xsq[p] - 2.0f * dot) + msq;
            if (d2 < best[p]) {  // strict <: first minimum wins (np.argmin)
                best[p] = d2;
                bidx[p] = k;
            }
        }
    }

#pragma unroll
    for (int p = 0; p < PTS; ++p) {
        const int i = base + p * BLK;
        if (i < n) out[i] = bidx[p];
    }
}

extern "C" void kernel_launch(void* const* d_in, const int* in_sizes, int n_in,
                              void* d_out, int out_size, void* d_ws, size_t ws_size,
                              hipStream_t stream) {
    const float* X = (const float*)d_in[0];
    const float* mus = (const float*)d_in[1];
    int* out = (int*)d_out;
    float* musq = (float*)d_ws;  // 256 floats of scratch

    const int n = in_sizes[0] / DIM;  // 500000

    musq_kernel<<<1, KPROTO, 0, stream>>>(mus, musq);

    const int grid = (n + BLK * PTS - 1) / (BLK * PTS);
    argmin_kernel<<<grid, BLK, 0, stream>>>(X, mus, musq, out, n);
}

// Round 5
// 173.068 us; speedup vs baseline: 4.0719x; 4.0719x over previous
//
#include <hip/hip_runtime.h>

// Nearest-prototype argmin: N=500k, K=256, D=64, fp32.
// R5: MFMA path. fp32 = bf16_hi + bf16_mid + bf16_lo (exact 3-way split);
// dot(x,mu) via 6 bf16 MFMA product-passes (i+j<=2), error ~2e-5 -- same
// class as fp32 reorder noise (absmax=0 in R1/R2). Waves own 64 protos as
// PERSISTENT register A-frags; X tiles stream through swizzled LDS as the
// shared B operand. argmin uses musq[k]-2*dot (x_sq constant per point).
// Safety net: top-2 margin < 0.05 -> flag bit 31 in out; fixup kernel
// recomputes flagged points in exact fp32 (R2-proven order). d_ws unused.

#define DIM 64
#define NPROTO 256
#define NBLK 512
#define MARGIN 0.05f

using f32x4  = __attribute__((ext_vector_type(4))) float;
using bf16x8 = __attribute__((ext_vector_type(8))) __bf16;
using bf16x4 = __attribute__((ext_vector_type(4))) __bf16;

__device__ __forceinline__ void split3(float x, __bf16& h0, __bf16& h1,
                                       __bf16& h2) {
    h0 = (__bf16)x;                 // RNE; x - (float)h0 exact in fp32
    float r = x - (float)h0;
    h1 = (__bf16)r;
    h2 = (__bf16)(r - (float)h1);   // residual fits bf16 (up to ~2^-33 dust)
}

__attribute__((amdgpu_waves_per_eu(2, 2)))   // force 256-VGPR budget (R4: allocator targeted 128 and spilled)
__global__ void __launch_bounds__(256)
argmin_mfma_kernel(const float* __restrict__ X,
                   const float* __restrict__ mus,
                   int* __restrict__ out, int n) {
    __shared__ __align__(16) __bf16 s_x[3][16][64];  // 6 KB, swizzled cols
    __shared__ float s_musq[NPROTO];                 // 1 KB
    __shared__ float s_cb[4][16];
    __shared__ float s_cb2[4][16];
    __shared__ int   s_ck[4][16];

    const int tid = threadIdx.x;
    const int w  = tid >> 6;   // wave 0..3 -> protos [w*64, w*64+64)
    const int l  = tid & 63;
    const int lp = l & 15;     // A-row / B-col / C-col lane index
    const int lg = l >> 4;     // k-group

    // ---- per-block musq (fp32, 4-stripe order as R1, absmax=0 heritage) ----
    {
        const float4* m4 = (const float4*)(mus + tid * DIM);
        float a0 = 0.f, a1 = 0.f, a2 = 0.f, a3 = 0.f;
#pragma unroll
        for (int q = 0; q < 16; ++q) {
            float4 v = m4[q];
            a0 = fmaf(v.x, v.x, a0); a1 = fmaf(v.y, v.y, a1);
            a2 = fmaf(v.z, v.z, a2); a3 = fmaf(v.w, v.w, a3);
        }
        s_musq[tid] = (a0 + a1) + (a2 + a3);
    }

    // ---- per-wave persistent A-frags: 64 protos x K64 x 3 levels ----
    // A-frag (16x16x32 bf16): lane holds A[row=lp][k = lg*8 .. lg*8+7] (+h*32)
    bf16x8 amu[4][2][3];
#pragma unroll
    for (int t = 0; t < 4; ++t) {
        const int p = w * 64 + t * 16 + lp;
#pragma unroll
        for (int h = 0; h < 2; ++h) {
            const float* src = mus + (size_t)p * DIM + h * 32 + lg * 8;
            const float4 va = *(const float4*)src;
            const float4 vb = *(const float4*)(src + 4);
            const float xs[8] = {va.x, va.y, va.z, va.w, vb.x, vb.y, vb.z, vb.w};
            bf16x8 m0, m1, m2;
#pragma unroll
            for (int e = 0; e < 8; ++e) {
                __bf16 h0, h1, h2;
                split3(xs[e], h0, h1, h2);
                m0[e] = h0; m1[e] = h1; m2[e] = h2;
            }
            amu[t][h][0] = m0; amu[t][h][1] = m1; amu[t][h][2] = m2;
        }
    }
    __syncthreads();

    // musq for this lane's 16 C-slots (C row = proto = lg*4 + reg, + t*16)
    float musq_reg[4][4];
#pragma unroll
    for (int t = 0; t < 4; ++t)
#pragma unroll
        for (int r = 0; r < 4; ++r)
            musq_reg[t][r] = s_musq[w * 64 + t * 16 + lg * 4 + r];

    // ---- tile range for this block ----
    const int ntiles = (n + 15) / 16;        // 31250
    const int q = ntiles / NBLK, rr = ntiles % NBLK;
    const int bid = blockIdx.x;
    const int t0  = bid * q + (bid < rr ? bid : rr);
    const int cnt = q + (bid < rr ? 1 : 0);

    const int srow = tid >> 4, spart = tid & 15;   // staging: row 0..15, 4-float chunk 0..15
    const int wgi = spart ^ ((srow & 7) << 1);     // swizzled 4-elem granule index

    // prologue: load tile t0's X chunk
    int pr = t0 * 16 + srow; pr = (pr < n) ? pr : (n - 1);
    float4 xreg = *(const float4*)(X + (size_t)pr * DIM + spart * 4);

    for (int it = 0; it < cnt; ++it) {
        const int tile = t0 + it;
        // stage: split 4 floats -> 3 bf16x4, swizzled LDS write
        {
            bf16x4 w0, w1, w2;
            const float xf[4] = {xreg.x, xreg.y, xreg.z, xreg.w};
#pragma unroll
            for (int e = 0; e < 4; ++e) {
                __bf16 h0, h1, h2;
                split3(xf[e], h0, h1, h2);
                w0[e] = h0; w1[e] = h1; w2[e] = h2;
            }
            ((bf16x4*)&s_x[0][srow][0])[wgi] = w0;
            ((bf16x4*)&s_x[1][srow][0])[wgi] = w1;
            ((bf16x4*)&s_x[2][srow][0])[wgi] = w2;
        }
        // issue next tile's global load (latency hides under compute, T14)
        float4 xnext = xreg;
        if (it + 1 < cnt) {
            int pn = (tile + 1) * 16 + srow; pn = (pn < n) ? pn : (n - 1);
            xnext = *(const float4*)(X + (size_t)pn * DIM + spart * 4);
        }
        __syncthreads();

        // B-frags: lane holds B[k = lg*8..+7 (+h*32)][col=lp], swizzled read
        bf16x8 bx[2][3];
#pragma unroll
        for (int h = 0; h < 2; ++h)
#pragma unroll
            for (int v = 0; v < 3; ++v)
                bx[h][v] = ((const bf16x8*)&s_x[v][lp][0])[(h * 4 + lg) ^ (lp & 7)];

        f32x4 acc[4] = {{0.f, 0.f, 0.f, 0.f}, {0.f, 0.f, 0.f, 0.f},
                        {0.f, 0.f, 0.f, 0.f}, {0.f, 0.f, 0.f, 0.f}};
        constexpr int PI[6] = {0, 1, 0, 2, 1, 0};
        constexpr int PJ[6] = {0, 0, 1, 0, 1, 2};
#pragma unroll
        for (int pp = 0; pp < 6; ++pp)
#pragma unroll
            for (int h = 0; h < 2; ++h)
#pragma unroll
                for (int t = 0; t < 4; ++t)
                    acc[t] = __builtin_amdgcn_mfma_f32_16x16x32_bf16(
                        amu[t][h][PI[pp]], bx[h][PJ[pp]], acc[t], 0, 0, 0);

        // epilogue: d2 = musq - 2*dot; in-lane top-2 over 16 protos (ascending)
        float b1 = 3.4e38f, b2 = 3.4e38f;
        int k1 = 0;
#pragma unroll
        for (int t = 0; t < 4; ++t)
#pragma unroll
            for (int r = 0; r < 4; ++r) {
                const float d2 = fmaf(-2.0f, acc[t][r], musq_reg[t][r]);
                const int kk = w * 64 + t * 16 + lg * 4 + r;
                const bool lt = d2 < b1;             // strict <: first min wins
                const float nb2 = lt ? b1 : fminf(d2, b2);
                b1 = lt ? d2 : b1;
                k1 = lt ? kk : k1;
                b2 = nb2;
            }
        // cross-lane over lg (lanes share point lp)
#pragma unroll
        for (int m = 16; m <= 32; m <<= 1) {
            const float ob1 = __shfl_xor(b1, m);
            const float ob2 = __shfl_xor(b2, m);
            const int   ok1 = __shfl_xor(k1, m);
            const float nb2 = fminf(fmaxf(b1, ob1), fminf(b2, ob2));
            const bool take = (ob1 < b1) || (ob1 == b1 && ok1 < k1);
            b1 = take ? ob1 : b1;
            k1 = take ? ok1 : k1;
            b2 = nb2;
        }
        if (lg == 0) { s_cb[w][lp] = b1; s_cb2[w][lp] = b2; s_ck[w][lp] = k1; }
        __syncthreads();

        // merge 4 waves (ascending w: tie keeps lower proto) + store
        if (tid < 16) {
            float f1 = s_cb[0][tid], f2 = s_cb2[0][tid];
            int fk = s_ck[0][tid];
#pragma unroll
            for (int ww = 1; ww < 4; ++ww) {
                const float ob1 = s_cb[ww][tid], ob2 = s_cb2[ww][tid];
                const int ok1 = s_ck[ww][tid];
                const float nb2 = fminf(fmaxf(f1, ob1), fminf(f2, ob2));
                if (ob1 < f1) { f1 = ob1; fk = ok1; }
                f2 = nb2;
            }
            const int i = tile * 16 + tid;
            if (i < n) {
                const unsigned flag = ((f2 - f1) < MARGIN) ? 0x80000000u : 0u;
                out[i] = (int)((unsigned)fk | flag);
            }
        }
        xreg = xnext;
    }
}

// Exact-fp32 recompute for margin-flagged points (wave-cooperative).
__global__ void __launch_bounds__(256)
fixup_kernel(const float* __restrict__ X, const float* __restrict__ mus,
             int* __restrict__ out, int n) {
    const int gw = (int)((blockIdx.x * blockDim.x + threadIdx.x) >> 6);
    const int l  = threadIdx.x & 63;
    const int NW = (int)((gridDim.x * blockDim.x) >> 6);
    const int chunk = (n + NW - 1) / NW;
    const int base = gw * chunk;
    const int end  = (base + chunk < n) ? (base + chunk) : n;
    for (int s = base; s < end; s += 64) {
        const int i = s + l;
        const int v = (i < end) ? out[i] : 0;
        const bool fl = (i < end) && ((unsigned)v & 0x80000000u);
        unsigned long long m = __ballot(fl);
        while (m) {
            const int src = (int)__ffsll((unsigned long long)m) - 1;
            m &= m - 1;
            const int pt = __shfl(i, src);
            const float4* xr = (const float4*)(X + (size_t)pt * DIM);
            float4 xv[16];
            float xa0 = 0.f, xa1 = 0.f, xa2 = 0.f, xa3 = 0.f;
#pragma unroll
            for (int qq = 0; qq < 16; ++qq) {
                xv[qq] = xr[qq];
                xa0 = fmaf(xv[qq].x, xv[qq].x, xa0);
                xa1 = fmaf(xv[qq].y, xv[qq].y, xa1);
                xa2 = fmaf(xv[qq].z, xv[qq].z, xa2);
                xa3 = fmaf(xv[qq].w, xv[qq].w, xa3);
            }
            const float xsq = (xa0 + xa1) + (xa2 + xa3);
            float b1 = 3.4e38f; int k1 = 0;
#pragma unroll
            for (int e = 0; e < 4; ++e) {
                const int p = l * 4 + e;
                const float4* mr = (const float4*)(mus + (size_t)p * DIM);
                float d0 = 0.f, d1 = 0.f, d2a = 0.f, d3 = 0.f;
                float q0 = 0.f, q1 = 0.f, q2 = 0.f, q3 = 0.f;
#pragma unroll
                for (int qq = 0; qq < 16; ++qq) {
                    const float4 mv = mr[qq];
                    d0 = fmaf(mv.x, xv[qq].x, d0);
                    d1 = fmaf(mv.y, xv[qq].y, d1);
                    d2a = fmaf(mv.z, xv[qq].z, d2a);
                    d3 = fmaf(mv.w, xv[qq].w, d3);
                    q0 = fmaf(mv.x, mv.x, q0);
                    q1 = fmaf(mv.y, mv.y, q1);
                    q2 = fmaf(mv.z, mv.z, q2);
                    q3 = fmaf(mv.w, mv.w, q3);
                }
                const float dot = (d0 + d1) + (d2a + d3);
                const float msq = (q0 + q1) + (q2 + q3);
                const float dd = (xsq - 2.0f * dot) + msq;
                if (dd < b1) { b1 = dd; k1 = p; }
            }
#pragma unroll
            for (int mm = 1; mm < 64; mm <<= 1) {
                const float ob = __shfl_xor(b1, mm);
                const int ok = __shfl_xor(k1, mm);
                if (ob < b1 || (ob == b1 && ok < k1)) { b1 = ob; k1 = ok; }
            }
            if (l == 0) out[pt] = k1;
        }
    }
}

extern "C" void kernel_launch(void* const* d_in, const int* in_sizes, int n_in,
                              void* d_out, int out_size, void* d_ws, size_t ws_size,
                              hipStream_t stream) {
    const float* X = (const float*)d_in[0];
    const float* mus = (const float*)d_in[1];
    int* out = (int*)d_out;
    const int n = in_sizes[0] / DIM;  // 500000

    argmin_mfma_kernel<<<NBLK, 256, 0, stream>>>(X, mus, out, n);
    fixup_kernel<<<256, 256, 0, stream>>>(X, mus, out, n);
}

// Round 6
// 111.744 us; speedup vs baseline: 6.3065x; 1.5488x over previous
//
#include <hip/hip_runtime.h>

// Nearest-prototype argmin: N=500k, K=256, D=64, fp32.
// R6: 3-pass bf16 MFMA (2-level Dekker split, err ~2e-4 << margin), 4
// waves/SIMD (NBLK=1024, waves_per_eu(4,8)), single barrier per tile with
// double-buffered s_x/s_cb, prefetch issued at tile top (hidden under
// MFMA+epilogue instead of drained dead at the barrier like R5). Margin
// 0.01 -> flagged fraction ~2-3%; fixup recomputes flagged in exact fp32
// (R2-proven order). d_ws unused.

#define DIM 64
#define NPROTO 256
#define NBLK 1024
#define MARGIN 0.01f

using f32x4  = __attribute__((ext_vector_type(4))) float;
using bf16x8 = __attribute__((ext_vector_type(8))) __bf16;
using bf16x4 = __attribute__((ext_vector_type(4))) __bf16;

__device__ __forceinline__ void split2(float x, __bf16& h0, __bf16& h1) {
    h0 = (__bf16)x;                 // RNE; x - (float)h0 exact in fp32
    h1 = (__bf16)(x - (float)h0);   // dropped residual ~2^-18 |x|
}

__attribute__((amdgpu_waves_per_eu(4, 8)))
__global__ void __launch_bounds__(256)
argmin_mfma_kernel(const float* __restrict__ X,
                   const float* __restrict__ mus,
                   int* __restrict__ out, int n) {
    __shared__ __align__(16) __bf16 s_x[2][2][16][64];  // [buf][lvl], 8 KB
    __shared__ float s_musq[NPROTO];
    __shared__ float s_cb[2][4][16];
    __shared__ float s_cb2[2][4][16];
    __shared__ int   s_ck[2][4][16];

    const int tid = threadIdx.x;
    const int w  = tid >> 6;   // wave 0..3 -> protos [w*64, w*64+64)
    const int l  = tid & 63;
    const int lp = l & 15;     // A-row / B-col lane index
    const int lg = l >> 4;     // k-group

    // ---- per-block musq (fp32, 4-stripe order, absmax=0 heritage) ----
    {
        const float4* m4 = (const float4*)(mus + tid * DIM);
        float a0 = 0.f, a1 = 0.f, a2 = 0.f, a3 = 0.f;
#pragma unroll
        for (int q = 0; q < 16; ++q) {
            float4 v = m4[q];
            a0 = fmaf(v.x, v.x, a0); a1 = fmaf(v.y, v.y, a1);
            a2 = fmaf(v.z, v.z, a2); a3 = fmaf(v.w, v.w, a3);
        }
        s_musq[tid] = (a0 + a1) + (a2 + a3);
    }

    // ---- per-wave persistent A-frags: 64 protos x K64 x 2 levels ----
    bf16x8 amu[4][2][2];
#pragma unroll
    for (int t = 0; t < 4; ++t) {
        const int p = w * 64 + t * 16 + lp;
#pragma unroll
        for (int h = 0; h < 2; ++h) {
            const float* src = mus + (size_t)p * DIM + h * 32 + lg * 8;
            const float4 va = *(const float4*)src;
            const float4 vb = *(const float4*)(src + 4);
            const float xs[8] = {va.x, va.y, va.z, va.w, vb.x, vb.y, vb.z, vb.w};
            bf16x8 m0, m1;
#pragma unroll
            for (int e = 0; e < 8; ++e) {
                __bf16 h0, h1;
                split2(xs[e], h0, h1);
                m0[e] = h0; m1[e] = h1;
            }
            amu[t][h][0] = m0; amu[t][h][1] = m1;
        }
    }

    // ---- tile range for this block ----
    const int ntiles = (n + 15) / 16;        // 31250
    const int q = ntiles / NBLK, rr = ntiles % NBLK;
    const int bid = blockIdx.x;
    const int t0  = bid * q + (bid < rr ? bid : rr);
    const int cnt = q + (bid < rr ? 1 : 0);

    const int srow = tid >> 4, spart = tid & 15;
    const int wgi = spart ^ ((srow & 7) << 1);  // swizzled 8B-granule index

#define STAGE(buf, v)                                                   \
    {                                                                   \
        bf16x4 w0, w1;                                                  \
        const float xf[4] = {(v).x, (v).y, (v).z, (v).w};               \
        _Pragma("unroll")                                               \
        for (int e = 0; e < 4; ++e) {                                   \
            __bf16 h0, h1;                                              \
            split2(xf[e], h0, h1);                                      \
            w0[e] = h0; w1[e] = h1;                                     \
        }                                                               \
        ((bf16x4*)&s_x[buf][0][srow][0])[wgi] = w0;                     \
        ((bf16x4*)&s_x[buf][1][srow][0])[wgi] = w1;                     \
    }

    // prologue: load + stage tile t0 into buf 0
    {
        int pr = t0 * 16 + srow; pr = (pr < n) ? pr : (n - 1);
        const float4 x0 = *(const float4*)(X + (size_t)pr * DIM + spart * 4);
        STAGE(0, x0)
    }
    __syncthreads();

    for (int it = 0; it < cnt; ++it) {
        const int tile = t0 + it;
        const int par = it & 1;
        const bool more = (it + 1 < cnt);

        // B-frags from s_x[par] (swizzled 16B reads; 2-way aliasing = free)
        bf16x8 bx[2][2];
#pragma unroll
        for (int h = 0; h < 2; ++h)
#pragma unroll
            for (int v = 0; v < 2; ++v)
                bx[h][v] =
                    ((const bf16x8*)&s_x[par][v][lp][0])[(h * 4 + lg) ^ (lp & 7)];

        // issue next tile's x load; consumed at STAGE below -> latency
        // hides under the MFMAs + epilogue (not drained at a barrier)
        float4 xnext;
        if (more) {
            int pn = (tile + 1) * 16 + srow; pn = (pn < n) ? pn : (n - 1);
            xnext = *(const float4*)(X + (size_t)pn * DIM + spart * 4);
        }

        f32x4 acc[4] = {{0.f, 0.f, 0.f, 0.f}, {0.f, 0.f, 0.f, 0.f},
                        {0.f, 0.f, 0.f, 0.f}, {0.f, 0.f, 0.f, 0.f}};
        constexpr int PI[3] = {0, 1, 0};
        constexpr int PJ[3] = {0, 0, 1};
#pragma unroll
        for (int pp = 0; pp < 3; ++pp)
#pragma unroll
            for (int h = 0; h < 2; ++h)
#pragma unroll
                for (int t = 0; t < 4; ++t)
                    acc[t] = __builtin_amdgcn_mfma_f32_16x16x32_bf16(
                        amu[t][h][PI[pp]], bx[h][PJ[pp]], acc[t], 0, 0, 0);

        // epilogue: d2 = musq - 2*dot (x_sq constant per point -> dropped);
        // in-lane top-2 over 16 slots, kk ascending -> strict < = first-min
        float b1 = 3.4e38f, b2 = 3.4e38f;
        int k1 = 0;
#pragma unroll
        for (int t = 0; t < 4; ++t)
#pragma unroll
            for (int r = 0; r < 4; ++r) {
                const int kk = w * 64 + t * 16 + lg * 4 + r;
                const float d2 = fmaf(-2.0f, acc[t][r], s_musq[kk]);
                const bool lt = d2 < b1;
                const float nb2 = lt ? b1 : fminf(d2, b2);
                b1 = lt ? d2 : b1;
                k1 = lt ? kk : k1;
                b2 = nb2;
            }
        // cross-lane over lg (lanes with same lp share a point)
#pragma unroll
        for (int m = 16; m <= 32; m <<= 1) {
            const float ob1 = __shfl_xor(b1, m);
            const float ob2 = __shfl_xor(b2, m);
            const int   ok1 = __shfl_xor(k1, m);
            const float nb2 = fminf(fmaxf(b1, ob1), fminf(b2, ob2));
            const bool take = (ob1 < b1) || (ob1 == b1 && ok1 < k1);
            b1 = take ? ob1 : b1;
            k1 = take ? ok1 : k1;
            b2 = nb2;
        }
        if (lg == 0) {
            s_cb[par][w][lp] = b1; s_cb2[par][w][lp] = b2; s_ck[par][w][lp] = k1;
        }

        // stage next tile into the other buffer (before the single barrier)
        if (more) STAGE(par ^ 1, xnext)

        __syncthreads();

        // merge 4 waves (ascending w: tie keeps lower proto) + store.
        // Reads s_cb[par]; next iter writes s_cb[par^1] -> no race.
        if (tid < 16) {
            float f1 = s_cb[par][0][tid], f2 = s_cb2[par][0][tid];
            int fk = s_ck[par][0][tid];
#pragma unroll
            for (int ww = 1; ww < 4; ++ww) {
                const float ob1 = s_cb[par][ww][tid], ob2 = s_cb2[par][ww][tid];
                const int ok1 = s_ck[par][ww][tid];
                const float nb2 = fminf(fmaxf(f1, ob1), fminf(f2, ob2));
                if (ob1 < f1) { f1 = ob1; fk = ok1; }
                f2 = nb2;
            }
            const int i = tile * 16 + tid;
            if (i < n) {
                const unsigned flag = ((f2 - f1) < MARGIN) ? 0x80000000u : 0u;
                out[i] = (int)((unsigned)fk | flag);
            }
        }
    }
#undef STAGE
}

// Exact-fp32 recompute for margin-flagged points (wave-cooperative).
__global__ void __launch_bounds__(256)
fixup_kernel(const float* __restrict__ X, const float* __restrict__ mus,
             int* __restrict__ out, int n) {
    const int gw = (int)((blockIdx.x * blockDim.x + threadIdx.x) >> 6);
    const int l  = threadIdx.x & 63;
    const int NW = (int)((gridDim.x * blockDim.x) >> 6);
    const int chunk = (n + NW - 1) / NW;
    const int base = gw * chunk;
    const int end  = (base + chunk < n) ? (base + chunk) : n;
    for (int s = base; s < end; s += 64) {
        const int i = s + l;
        const int v = (i < end) ? out[i] : 0;
        const bool fl = (i < end) && ((unsigned)v & 0x80000000u);
        unsigned long long m = __ballot(fl);
        while (m) {
            const int src = (int)__ffsll((unsigned long long)m) - 1;
            m &= m - 1;
            const int pt = __shfl(i, src);
            const float4* xr = (const float4*)(X + (size_t)pt * DIM);
            float4 xv[16];
            float xa0 = 0.f, xa1 = 0.f, xa2 = 0.f, xa3 = 0.f;
#pragma unroll
            for (int qq = 0; qq < 16; ++qq) {
                xv[qq] = xr[qq];
                xa0 = fmaf(xv[qq].x, xv[qq].x, xa0);
                xa1 = fmaf(xv[qq].y, xv[qq].y, xa1);
                xa2 = fmaf(xv[qq].z, xv[qq].z, xa2);
                xa3 = fmaf(xv[qq].w, xv[qq].w, xa3);
            }
            const float xsq = (xa0 + xa1) + (xa2 + xa3);
            float b1 = 3.4e38f; int k1 = 0;
#pragma unroll
            for (int e = 0; e < 4; ++e) {
                const int p = l * 4 + e;
                const float4* mr = (const float4*)(mus + (size_t)p * DIM);
                float d0 = 0.f, d1 = 0.f, d2a = 0.f, d3 = 0.f;
                float q0 = 0.f, q1 = 0.f, q2 = 0.f, q3 = 0.f;
#pragma unroll
                for (int qq = 0; qq < 16; ++qq) {
                    const float4 mv = mr[qq];
                    d0 = fmaf(mv.x, xv[qq].x, d0);
                    d1 = fmaf(mv.y, xv[qq].y, d1);
                    d2a = fmaf(mv.z, xv[qq].z, d2a);
                    d3 = fmaf(mv.w, xv[qq].w, d3);
                    q0 = fmaf(mv.x, mv.x, q0);
                    q1 = fmaf(mv.y, mv.y, q1);
                    q2 = fmaf(mv.z, mv.z, q2);
                    q3 = fmaf(mv.w, mv.w, q3);
                }
                const float dot = (d0 + d1) + (d2a + d3);
                const float msq = (q0 + q1) + (q2 + q3);
                const float dd = (xsq - 2.0f * dot) + msq;
                if (dd < b1) { b1 = dd; k1 = p; }
            }
#pragma unroll
            for (int mm = 1; mm < 64; mm <<= 1) {
                const float ob = __shfl_xor(b1, mm);
                const int ok = __shfl_xor(k1, mm);
                if (ob < b1 || (ob == b1 && ok < k1)) { b1 = ob; k1 = ok; }
            }
            if (l == 0) out[pt] = k1;
        }
    }
}

extern "C" void kernel_launch(void* const* d_in, const int* in_sizes, int n_in,
                              void* d_out, int out_size, void* d_ws, size_t ws_size,
                              hipStream_t stream) {
    const float* X = (const float*)d_in[0];
    const float* mus = (const float*)d_in[1];
    int* out = (int*)d_out;
    const int n = in_sizes[0] / DIM;  // 500000

    argmin_mfma_kernel<<<NBLK, 256, 0, stream>>>(X, mus, out, n);
    fixup_kernel<<<512, 256, 0, stream>>>(X, mus, out, n);
}

// Round 7
// 100.931 us; speedup vs baseline: 6.9821x; 1.1071x over previous
//
#include <hip/hip_runtime.h>

// Nearest-prototype argmin: N=500k, K=256, D=64, fp32.
// R7: same proven MFMA numerics as R6 (3-pass bf16, 2-level split, margin
// 0.01 + exact-fp32 fixup). Changes: NBLK 2048 (8 blocks/CU = 8 waves/SIMD;
// R6's L3-warm replay at identical 91 us proved latency-bound, not BW) and
// flagged-point COMPACTION into a d_ws list (fixup reads the dense list
// instead of scanning 500k flag bits). Fallback to flag-bit scan if ws too
// small. VGPR must stay <=64 for 8 waves/SIMD.

#define DIM 64
#define NPROTO 256
#define NBLK 2048
#define MARGIN 0.01f

using f32x4  = __attribute__((ext_vector_type(4))) float;
using bf16x8 = __attribute__((ext_vector_type(8))) __bf16;
using bf16x4 = __attribute__((ext_vector_type(4))) __bf16;

__device__ __forceinline__ void split2(float x, __bf16& h0, __bf16& h1) {
    h0 = (__bf16)x;                 // RNE; x - (float)h0 exact in fp32
    h1 = (__bf16)(x - (float)h0);   // dropped residual ~2^-18 |x|
}

__attribute__((amdgpu_waves_per_eu(4, 8)))
__global__ void __launch_bounds__(256)
argmin_mfma_kernel(const float* __restrict__ X,
                   const float* __restrict__ mus,
                   int* __restrict__ out,
                   unsigned* __restrict__ ws_count,
                   int* __restrict__ ws_list,
                   int use_list, int n) {
    __shared__ __align__(16) __bf16 s_x[2][2][16][64];  // [buf][lvl], 8 KB
    __shared__ float s_musq[NPROTO];
    __shared__ float s_cb[2][4][16];
    __shared__ float s_cb2[2][4][16];
    __shared__ int   s_ck[2][4][16];

    const int tid = threadIdx.x;
    const int w  = tid >> 6;   // wave 0..3 -> protos [w*64, w*64+64)
    const int l  = tid & 63;
    const int lp = l & 15;     // A-row / B-col lane index
    const int lg = l >> 4;     // k-group

    // ---- per-block musq (fp32, 4-stripe order, absmax=0 heritage) ----
    {
        const float4* m4 = (const float4*)(mus + tid * DIM);
        float a0 = 0.f, a1 = 0.f, a2 = 0.f, a3 = 0.f;
#pragma unroll
        for (int q = 0; q < 16; ++q) {
            float4 v = m4[q];
            a0 = fmaf(v.x, v.x, a0); a1 = fmaf(v.y, v.y, a1);
            a2 = fmaf(v.z, v.z, a2); a3 = fmaf(v.w, v.w, a3);
        }
        s_musq[tid] = (a0 + a1) + (a2 + a3);
    }

    // ---- per-wave persistent A-frags: 64 protos x K64 x 2 levels ----
    bf16x8 amu[4][2][2];
#pragma unroll
    for (int t = 0; t < 4; ++t) {
        const int p = w * 64 + t * 16 + lp;
#pragma unroll
        for (int h = 0; h < 2; ++h) {
            const float* src = mus + (size_t)p * DIM + h * 32 + lg * 8;
            const float4 va = *(const float4*)src;
            const float4 vb = *(const float4*)(src + 4);
            const float xs[8] = {va.x, va.y, va.z, va.w, vb.x, vb.y, vb.z, vb.w};
            bf16x8 m0, m1;
#pragma unroll
            for (int e = 0; e < 8; ++e) {
                __bf16 h0, h1;
                split2(xs[e], h0, h1);
                m0[e] = h0; m1[e] = h1;
            }
            amu[t][h][0] = m0; amu[t][h][1] = m1;
        }
    }

    // ---- tile range for this block ----
    const int ntiles = (n + 15) / 16;        // 31250
    const int q = ntiles / NBLK, rr = ntiles % NBLK;
    const int bid = blockIdx.x;
    const int t0  = bid * q + (bid < rr ? bid : rr);
    const int cnt = q + (bid < rr ? 1 : 0);

    const int srow = tid >> 4, spart = tid & 15;
    const int wgi = spart ^ ((srow & 7) << 1);  // swizzled 8B-granule index

#define STAGE(buf, v)                                                   \
    {                                                                   \
        bf16x4 w0, w1;                                                  \
        const float xf[4] = {(v).x, (v).y, (v).z, (v).w};               \
        _Pragma("unroll")                                               \
        for (int e = 0; e < 4; ++e) {                                   \
            __bf16 h0, h1;                                              \
            split2(xf[e], h0, h1);                                      \
            w0[e] = h0; w1[e] = h1;                                     \
        }                                                               \
        ((bf16x4*)&s_x[buf][0][srow][0])[wgi] = w0;                     \
        ((bf16x4*)&s_x[buf][1][srow][0])[wgi] = w1;                     \
    }

    // prologue: load + stage tile t0 into buf 0
    {
        int pr = t0 * 16 + srow; pr = (pr < n) ? pr : (n - 1);
        const float4 x0 = *(const float4*)(X + (size_t)pr * DIM + spart * 4);
        STAGE(0, x0)
    }
    __syncthreads();

    for (int it = 0; it < cnt; ++it) {
        const int tile = t0 + it;
        const int par = it & 1;
        const bool more = (it + 1 < cnt);

        // B-frags from s_x[par] (swizzled 16B reads; 2-way aliasing = free)
        bf16x8 bx[2][2];
#pragma unroll
        for (int h = 0; h < 2; ++h)
#pragma unroll
            for (int v = 0; v < 2; ++v)
                bx[h][v] =
                    ((const bf16x8*)&s_x[par][v][lp][0])[(h * 4 + lg) ^ (lp & 7)];

        // issue next tile's x load; consumed at STAGE below -> latency
        // hides under the MFMAs + epilogue
        float4 xnext;
        if (more) {
            int pn = (tile + 1) * 16 + srow; pn = (pn < n) ? pn : (n - 1);
            xnext = *(const float4*)(X + (size_t)pn * DIM + spart * 4);
        }

        f32x4 acc[4] = {{0.f, 0.f, 0.f, 0.f}, {0.f, 0.f, 0.f, 0.f},
                        {0.f, 0.f, 0.f, 0.f}, {0.f, 0.f, 0.f, 0.f}};
        constexpr int PI[3] = {0, 1, 0};
        constexpr int PJ[3] = {0, 0, 1};
#pragma unroll
        for (int pp = 0; pp < 3; ++pp)
#pragma unroll
            for (int h = 0; h < 2; ++h)
#pragma unroll
                for (int t = 0; t < 4; ++t)
                    acc[t] = __builtin_amdgcn_mfma_f32_16x16x32_bf16(
                        amu[t][h][PI[pp]], bx[h][PJ[pp]], acc[t], 0, 0, 0);

        // epilogue: d2 = musq - 2*dot (x_sq constant per point -> dropped);
        // in-lane top-2 over 16 slots, kk ascending -> strict < = first-min
        float b1 = 3.4e38f, b2 = 3.4e38f;
        int k1 = 0;
#pragma unroll
        for (int t = 0; t < 4; ++t)
#pragma unroll
            for (int r = 0; r < 4; ++r) {
                const int kk = w * 64 + t * 16 + lg * 4 + r;
                const float d2 = fmaf(-2.0f, acc[t][r], s_musq[kk]);
                const bool lt = d2 < b1;
                const float nb2 = lt ? b1 : fminf(d2, b2);
                b1 = lt ? d2 : b1;
                k1 = lt ? kk : k1;
                b2 = nb2;
            }
        // cross-lane over lg (lanes with same lp share a point)
#pragma unroll
        for (int m = 16; m <= 32; m <<= 1) {
            const float ob1 = __shfl_xor(b1, m);
            const float ob2 = __shfl_xor(b2, m);
            const int   ok1 = __shfl_xor(k1, m);
            const float nb2 = fminf(fmaxf(b1, ob1), fminf(b2, ob2));
            const bool take = (ob1 < b1) || (ob1 == b1 && ok1 < k1);
            b1 = take ? ob1 : b1;
            k1 = take ? ok1 : k1;
            b2 = nb2;
        }
        if (lg == 0) {
            s_cb[par][w][lp] = b1; s_cb2[par][w][lp] = b2; s_ck[par][w][lp] = k1;
        }

        // stage next tile into the other buffer (before the single barrier)
        if (more) STAGE(par ^ 1, xnext)

        __syncthreads();

        // merge 4 waves (ascending w: tie keeps lower proto) + store.
        if (tid < 16) {
            float f1 = s_cb[par][0][tid], f2 = s_cb2[par][0][tid];
            int fk = s_ck[par][0][tid];
#pragma unroll
            for (int ww = 1; ww < 4; ++ww) {
                const float ob1 = s_cb[par][ww][tid], ob2 = s_cb2[par][ww][tid];
                const int ok1 = s_ck[par][ww][tid];
                const float nb2 = fminf(fmaxf(f1, ob1), fminf(f2, ob2));
                if (ob1 < f1) { f1 = ob1; fk = ok1; }
                f2 = nb2;
            }
            const int i = tile * 16 + tid;
            if (i < n) {
                const bool close = (f2 - f1) < MARGIN;
                if (use_list) {
                    out[i] = fk;  // clean index; flagged points go to the list
                    if (close) {
                        const unsigned idx = atomicAdd(ws_count, 1u);
                        ws_list[idx] = i;  // capacity >= n guaranteed by host
                    }
                } else {
                    out[i] = (int)((unsigned)fk | (close ? 0x80000000u : 0u));
                }
            }
        }
    }
#undef STAGE
}

// Exact-fp32 wave-cooperative recompute of one point (R2-proven order).
__device__ __forceinline__ int recompute_point(const float* __restrict__ X,
                                               const float* __restrict__ mus,
                                               int pt, int l) {
    const float4* xr = (const float4*)(X + (size_t)pt * DIM);
    float4 xv[16];
    float xa0 = 0.f, xa1 = 0.f, xa2 = 0.f, xa3 = 0.f;
#pragma unroll
    for (int qq = 0; qq < 16; ++qq) {
        xv[qq] = xr[qq];
        xa0 = fmaf(xv[qq].x, xv[qq].x, xa0);
        xa1 = fmaf(xv[qq].y, xv[qq].y, xa1);
        xa2 = fmaf(xv[qq].z, xv[qq].z, xa2);
        xa3 = fmaf(xv[qq].w, xv[qq].w, xa3);
    }
    const float xsq = (xa0 + xa1) + (xa2 + xa3);
    float b1 = 3.4e38f; int k1 = 0;
#pragma unroll
    for (int e = 0; e < 4; ++e) {
        const int p = l * 4 + e;
        const float4* mr = (const float4*)(mus + (size_t)p * DIM);
        float d0 = 0.f, d1 = 0.f, d2a = 0.f, d3 = 0.f;
        float q0 = 0.f, q1 = 0.f, q2 = 0.f, q3 = 0.f;
#pragma unroll
        for (int qq = 0; qq < 16; ++qq) {
            const float4 mv = mr[qq];
            d0 = fmaf(mv.x, xv[qq].x, d0);
            d1 = fmaf(mv.y, xv[qq].y, d1);
            d2a = fmaf(mv.z, xv[qq].z, d2a);
            d3 = fmaf(mv.w, xv[qq].w, d3);
            q0 = fmaf(mv.x, mv.x, q0);
            q1 = fmaf(mv.y, mv.y, q1);
            q2 = fmaf(mv.z, mv.z, q2);
            q3 = fmaf(mv.w, mv.w, q3);
        }
        const float dot = (d0 + d1) + (d2a + d3);
        const float msq = (q0 + q1) + (q2 + q3);
        const float dd = (xsq - 2.0f * dot) + msq;
        if (dd < b1) { b1 = dd; k1 = p; }
    }
#pragma unroll
    for (int mm = 1; mm < 64; mm <<= 1) {
        const float ob = __shfl_xor(b1, mm);
        const int ok = __shfl_xor(k1, mm);
        if (ob < b1 || (ob == b1 && ok < k1)) { b1 = ob; k1 = ok; }
    }
    return k1;
}

// List-driven fixup: one wave per flagged point, grid-stride over the list.
__global__ void __launch_bounds__(256)
fixup_list_kernel(const float* __restrict__ X, const float* __restrict__ mus,
                  const unsigned* __restrict__ ws_count,
                  const int* __restrict__ ws_list, int* __restrict__ out) {
    const int gw = (int)((blockIdx.x * blockDim.x + threadIdx.x) >> 6);
    const int l  = threadIdx.x & 63;
    const int NW = (int)((gridDim.x * blockDim.x) >> 6);
    const int nf = (int)*ws_count;
    for (int j = gw; j < nf; j += NW) {
        const int pt = ws_list[j];
        const int k1 = recompute_point(X, mus, pt, l);
        if (l == 0) out[pt] = k1;
    }
}

// Fallback scan fixup (flag bit 31 in out), used if ws too small.
__global__ void __launch_bounds__(256)
fixup_scan_kernel(const float* __restrict__ X, const float* __restrict__ mus,
                  int* __restrict__ out, int n) {
    const int gw = (int)((blockIdx.x * blockDim.x + threadIdx.x) >> 6);
    const int l  = threadIdx.x & 63;
    const int NW = (int)((gridDim.x * blockDim.x) >> 6);
    const int chunk = (n + NW - 1) / NW;
    const int base = gw * chunk;
    const int end  = (base + chunk < n) ? (base + chunk) : n;
    for (int s = base; s < end; s += 64) {
        const int i = s + l;
        const int v = (i < end) ? out[i] : 0;
        const bool fl = (i < end) && ((unsigned)v & 0x80000000u);
        unsigned long long m = __ballot(fl);
        while (m) {
            const int src = (int)__ffsll((unsigned long long)m) - 1;
            m &= m - 1;
            const int pt = __shfl(i, src);
            const int k1 = recompute_point(X, mus, pt, l);
            if (l == 0) out[pt] = k1;
        }
    }
}

extern "C" void kernel_launch(void* const* d_in, const int* in_sizes, int n_in,
                              void* d_out, int out_size, void* d_ws, size_t ws_size,
                              hipStream_t stream) {
    const float* X = (const float*)d_in[0];
    const float* mus = (const float*)d_in[1];
    int* out = (int*)d_out;
    const int n = in_sizes[0] / DIM;  // 500000

    unsigned* ws_count = (unsigned*)d_ws;
    int* ws_list = (int*)((char*)d_ws + 16);
    const int use_list = (ws_size >= 16 + (size_t)n * 4) ? 1 : 0;

    if (use_list) {
        hipMemsetAsync(d_ws, 0, 16, stream);  // reset append counter
    }

    argmin_mfma_kernel<<<NBLK, 256, 0, stream>>>(X, mus, out, ws_count,
                                                 ws_list, use_list, n);
    if (use_list) {
        fixup_list_kernel<<<256, 256, 0, stream>>>(X, mus, ws_count, ws_list,
                                                   out);
    } else {
        fixup_scan_kernel<<<512, 256, 0, stream>>>(X, mus, out, n);
    }
}